// Round 1
// 569.303 us; speedup vs baseline: 1.4487x; 1.4487x over previous
//
#include <hip/hip_runtime.h>

// Projection: out[b,f,e] = sum_d x[b, idx[f,d]] * W[f,d,e] + bias[f,e]
// B=524288, F=23, DMAX=4, E=10, TOTAL=65.  W pre-masked past dims[f].
//
// v2: row-tiled LDS kernel. Previous version was latency/L1-issue bound
// (11 address-divergent VMEM per 8 output bytes; VALUBusy 18%, HBM 17.5%).
// Now: block stages 64 contiguous x-rows (16.6 KB, 16B-aligned because rows
// are packed) into LDS with coalesced float4 loads; each thread owns a fixed
// (f, e-pair) so idx/W/bias live in registers for the whole block. Inner loop:
// 4 ds_read_b32 (<=2-way bank alias, broadcast across same-f lanes) + 8 FMA +
// 1 coalesced dwordx2 store. Expect HBM-write-bound (~471 MB out).

#define PROJ_B     524288
#define PROJ_TOTAL 65
#define PROJ_F     23
#define PROJ_DMAX  4
#define PROJ_E     10
#define PROJ_COLS  (PROJ_F * PROJ_E)   // 230
#define PROJ_HALF  (PROJ_COLS / 2)     // 115 float2 per row
#define ROWS       64                  // rows per block
#define TILE_DW    (ROWS * PROJ_TOTAL) // 4160 dwords = 16640 B LDS
#define TILE_F4    (TILE_DW / 4)       // 1040 float4

__global__ __launch_bounds__(256, 8)   // force VGPR<=64 -> 8 waves/SIMD
void Projection_5171140624940_kernel(const float* __restrict__ x,
                                     const float* __restrict__ W,
                                     const float* __restrict__ bias,
                                     const int*   __restrict__ idx,
                                     float*       __restrict__ out) {
    __shared__ float xs[TILE_DW];

    const int tid = threadIdx.x;
    const long long b0 = (long long)blockIdx.x * ROWS;   // first row of tile

    // ---- stage x tile: rows are packed, so the tile is one contiguous,
    //      16B-aligned run of 4160 dwords. 256 threads x 4 float4 + 16 tail.
    const float4* __restrict__ src = (const float4*)(x + b0 * PROJ_TOTAL);
    float4* dst = (float4*)xs;
    #pragma unroll
    for (int i = 0; i < 4; ++i)
        dst[i * 256 + tid] = src[i * 256 + tid];
    if (tid < TILE_F4 - 4 * 256)                         // 16 remaining
        dst[4 * 256 + tid] = src[4 * 256 + tid];

    // ---- per-thread fixed (f, e-pair); waves: {ro=0: lanes c2 0..127},
    //      {ro=1: same}, active when c2 < 115.
    const int c2 = tid & 127;
    const int ro = tid >> 7;                             // sub-row 0/1
    const bool active = (c2 < PROJ_HALF);
    const int c  = active ? (c2 * 2) : 0;                // even column 0..228
    const int f  = c / PROJ_E;                           // const-div -> magic mul
    const int e  = c - f * PROJ_E;

    // idx/W/bias loaded ONCE per thread (L1-resident), live in registers.
    const int4 id = *(const int4*)(idx + f * PROJ_DMAX);
    const float* __restrict__ Wf = W + f * (PROJ_DMAX * PROJ_E) + e;
    const float2 w0 = *(const float2*)(Wf + 0 * PROJ_E);
    const float2 w1 = *(const float2*)(Wf + 1 * PROJ_E);
    const float2 w2 = *(const float2*)(Wf + 2 * PROJ_E);
    const float2 w3 = *(const float2*)(Wf + 3 * PROJ_E);
    const float2 bb = *(const float2*)(bias + f * PROJ_E + e);

    __syncthreads();

    if (active) {
        float* op = out + (b0 + ro) * PROJ_COLS + c;
        #pragma unroll 4
        for (int r = ro; r < ROWS; r += 2) {
            const float* __restrict__ xr = xs + r * PROJ_TOTAL;
            const float x0 = xr[id.x];
            const float x1 = xr[id.y];
            const float x2 = xr[id.z];
            const float x3 = xr[id.w];
            float2 acc = bb;
            acc.x = fmaf(x0, w0.x, fmaf(x1, w1.x, fmaf(x2, w2.x, fmaf(x3, w3.x, acc.x))));
            acc.y = fmaf(x0, w0.y, fmaf(x1, w1.y, fmaf(x2, w2.y, fmaf(x3, w3.y, acc.y))));
            *(float2*)op = acc;                          // coalesced dwordx2
            op += 2 * PROJ_COLS;
        }
    }
}

extern "C" void kernel_launch(void* const* d_in, const int* in_sizes, int n_in,
                              void* d_out, int out_size, void* d_ws, size_t ws_size,
                              hipStream_t stream) {
    const float* x    = (const float*)d_in[0];   // (B, 65)
    const float* W    = (const float*)d_in[1];   // (23, 4, 10)
    const float* bias = (const float*)d_in[2];   // (23, 10)
    const int*   idx  = (const int*)d_in[3];     // (23, 4)
    float* out = (float*)d_out;                  // (B, 23, 10)

    const int grid  = PROJ_B / ROWS;             // 8192 blocks
    const int block = 256;

    Projection_5171140624940_kernel<<<grid, block, 0, stream>>>(x, W, bias, idx, out);
}